// Round 6
// baseline (239.020 us; speedup 1.0000x reference)
//
#include <hip/hip_runtime.h>
#include <hip/hip_bf16.h>
#include <stdint.h>

#define NUMH 16
#define HD   64
#define HID  1024
#define SEQ  2048
#define BATCH 2
#define NTOK (BATCH*SEQ)   // 4096
#define LN_EPS 1e-5f

typedef __attribute__((ext_vector_type(8)))  short  short8;   // 8 bf16 (4 VGPRs)
typedef __attribute__((ext_vector_type(4)))  float  f32x4;
typedef __attribute__((ext_vector_type(16))) float  f32x16;

#define AS1 __attribute__((address_space(1)))
#define AS3 __attribute__((address_space(3)))

__device__ __forceinline__ void gload_lds16(const void* g, void* l) {
  // LDS dest = wave-uniform base + lane*16 (HW); global addr is per-lane.
  __builtin_amdgcn_global_load_lds((const AS1 void*)g, (AS3 void*)l, 16, 0, 0);
}

__device__ __forceinline__ unsigned short f2bf(float f) {
  union { float f; unsigned u; } v; v.f = f;
  unsigned u = v.u;
  u += 0x7fffu + ((u >> 16) & 1u);   // RNE
  return (unsigned short)(u >> 16);
}

__device__ __forceinline__ f32x4 mfma16x16x32(short8 a, short8 b, f32x4 c) {
  return __builtin_amdgcn_mfma_f32_16x16x32_bf16(a, b, c, 0, 0, 0);
}
__device__ __forceinline__ f32x16 mfma32x32x16(short8 a, short8 b, f32x16 c) {
  return __builtin_amdgcn_mfma_f32_32x32x16_bf16(a, b, c, 0, 0, 0);
}

// pack two f32 -> dword of 2 bf16 (lo = first arg), HW RNE
__device__ __forceinline__ unsigned cvtpk(float lo, float hi) {
  unsigned r;
  asm("v_cvt_pk_bf16_f32 %0, %1, %2" : "=v"(r) : "v"(lo), "v"(hi));
  return r;
}
// swap upper 32 lanes of a with lower 32 lanes of b (both modified)
__device__ __forceinline__ void perm32swap(unsigned &a, unsigned &b) {
  asm volatile("v_permlane32_swap_b32 %0, %1" : "+v"(a), "+v"(b));
}
// cross-half (lane i <-> lane i^32) reduce helpers via permlane32_swap
__device__ __forceinline__ float xhalf_max(float x) {
  union { float f; unsigned u; } a, b; a.f = x; b.f = x;
  perm32swap(a.u, b.u);
  return fmaxf(a.f, b.f);
}
__device__ __forceinline__ float xhalf_sum(float x) {
  union { float f; unsigned u; } a, b; a.f = x; b.f = x;
  perm32swap(a.u, b.u);
  return a.f + b.f;
}

// -------- fused: weight transposes (z=0..3) + x fp32->bf16 conversion (z=4) --------
__global__ void k_prep(const float* __restrict__ Wq, const float* __restrict__ Wk,
                       const float* __restrict__ Wv, const float* __restrict__ Wo,
                       const float* __restrict__ x,
                       unsigned short* __restrict__ WqkvT, unsigned short* __restrict__ WoT,
                       unsigned short* __restrict__ xb) {
  int z = blockIdx.z;
  int tx = threadIdx.x, ty = threadIdx.y;           // 32 x 8
  if (z == 4) {
    // x conversion: 1024 blocks x 256 thr x 4 f32x4
    int tid = ty * 32 + tx;
    size_t i0 = ((size_t)(blockIdx.y * 32 + blockIdx.x) * 256 + tid) * 4;
    #pragma unroll
    for (int u = 0; u < 4; ++u) {
      f32x4 v = ((const f32x4*)x)[i0 + u];
      unsigned short* o = xb + (i0 + u) * 4;
      o[0] = f2bf(v[0]); o[1] = f2bf(v[1]); o[2] = f2bf(v[2]); o[3] = f2bf(v[3]);
    }
    return;
  }
  __shared__ float t[32][33];
  const float* in = (z == 0) ? Wq : (z == 1) ? Wk : (z == 2) ? Wv : Wo;
  unsigned short* out = (z < 3) ? WqkvT + (size_t)z * HID * HID : WoT;
  int x0 = blockIdx.x * 32, y0 = blockIdx.y * 32;
  for (int j = 0; j < 32; j += 8)
    t[ty + j][tx] = in[(y0 + ty + j) * HID + x0 + tx];
  __syncthreads();
  for (int j = 0; j < 32; j += 8)
    out[(x0 + ty + j) * HID + y0 + tx] = f2bf(t[tx][ty + j]);
}

// ---------------- GEMM: C[M][N] = A[M][K](bf16) * BT[N][K](bf16)^T ----------------
// m97 geometry: 128x128 tile, BK=64, 4 waves (2x2). 1D grid with XCD 2D-chunked
// mapping (T1): xcd = id&7 owns an 8x12 (MODE0) / 8x4 (MODE1) block region ->
// per-XCD L2 footprint ~5MB instead of ~14MB. Mapping is bijective:
//   MODE0: (xcd&3,i2&7)->rb in [0,32), (xcd>>2,i2>>3)->cb in [0,24), 768 blocks.
//   MODE1: (xcd&3,i2&7)->rb in [0,32), (xcd>>2,i2>>3)->cb in [0,8),  256 blocks.
// MODE 0: QKV epilogue: scatter to Q/K/V head layouts [BH][S][64], add bias.
// MODE 1: fp32 epilogue with fused residual: outF = acc + bias0[col] + resid[row][col].
template<int MODE>
__global__ __launch_bounds__(256, 2)
void k_gemm(const unsigned short* __restrict__ A, const unsigned short* __restrict__ BT,
            int M, int N, int K,
            const float* __restrict__ bias0, const float* __restrict__ bias1,
            const float* __restrict__ bias2, const float* __restrict__ resid,
            unsigned short* __restrict__ outQ, unsigned short* __restrict__ outK,
            unsigned short* __restrict__ outV, float* __restrict__ outF) {
  const int tid  = threadIdx.x;
  const int lane = tid & 63, wave = tid >> 6;
  const int l15 = lane & 15, lhi = lane >> 4;
  const int orig = blockIdx.x;
  const int xcd = orig & 7, i2 = orig >> 3;
  const int rb  = (xcd & 3) * 8 + (i2 & 7);
  const int cb2 = (MODE == 0) ? (xcd >> 2) * 12 + (i2 >> 3)
                              : (xcd >> 2) * 4  + (i2 >> 3);
  const int row0 = rb * 128, col0 = cb2 * 128;
  const int wrow = (wave >> 1) * 64, wcol = (wave & 1) * 64;

  __shared__ unsigned short As[128 * 64];   // [128 row][64 bf16] = 128B rows
  __shared__ unsigned short Bs[128 * 64];

  f32x4 acc[4][4] = {};

  for (int kt = 0; kt < K; kt += 64) {
    #pragma unroll
    for (int c = 0; c < 4; ++c) {
      int base = wave * 1024 + c * 4096;            // byte base (wave-uniform)
      int o = base + lane * 16;                     // this lane's byte offset
      int r = o >> 7, cb = o & 127;                 // row, col-byte (128B rows)
      gload_lds16(A  + (size_t)(row0 + r) * K + kt + (cb >> 1), As + (base >> 1));
      gload_lds16(BT + (size_t)(col0 + r) * K + kt + (cb >> 1), Bs + (base >> 1));
    }
    __syncthreads();

    #pragma unroll
    for (int kk = 0; kk < 2; ++kk) {
      short8 af[4], bf[4];
      #pragma unroll
      for (int m = 0; m < 4; ++m)
        af[m] = *(const short8*)(As + (wrow + m * 16 + l15) * 64 + kk * 32 + lhi * 8);
      #pragma unroll
      for (int n = 0; n < 4; ++n)
        bf[n] = *(const short8*)(Bs + (wcol + n * 16 + l15) * 64 + kk * 32 + lhi * 8);
      #pragma unroll
      for (int m = 0; m < 4; ++m)
        #pragma unroll
        for (int n = 0; n < 4; ++n)
          acc[m][n] = mfma16x16x32(af[m], bf[n], acc[m][n]);
    }
    __syncthreads();
  }

  #pragma unroll
  for (int m = 0; m < 4; ++m)
    #pragma unroll
    for (int n = 0; n < 4; ++n) {
      int col = col0 + wcol + n * 16 + l15;
      #pragma unroll
      for (int j = 0; j < 4; ++j) {
        int row = row0 + wrow + m * 16 + lhi * 4 + j;
        float v = acc[m][n][j];
        if (MODE == 0) {
          int proj = col >> 10, d = col & 1023;
          int h = d >> 6, hd = d & 63;
          int b = row >> 11, s = row & 2047;
          const float* bias = (proj == 0) ? bias0 : (proj == 1) ? bias1 : bias2;
          unsigned short* dst = (proj == 0) ? outQ : (proj == 1) ? outK : outV;
          dst[((size_t)((b * NUMH + h) * SEQ + s) << 6) + hd] = f2bf(v + bias[d]);
        } else {
          size_t idx = (size_t)row * N + col;
          outF[idx] = v + bias0[col] + resid[idx];
        }
      }
    }
}

// ---------------- V [BH][S][64] -> VT [BH][64][S] (bf16) ----------------
__global__ void k_vtrans(const unsigned short* __restrict__ V, unsigned short* __restrict__ VT) {
  __shared__ unsigned short t[64][65];
  int bh = blockIdx.y, s0 = blockIdx.x * 64;
  int tid = threadIdx.x;
  for (int it = 0; it < 16; ++it) {
    int idx = it * 256 + tid;
    int r = idx >> 6, c = idx & 63;
    t[r][c] = V[(size_t)(bh * SEQ + s0 + r) * 64 + c];
  }
  __syncthreads();
  for (int it = 0; it < 16; ++it) {
    int idx = it * 256 + tid;
    int d = idx >> 6, sl = idx & 63;
    VT[(size_t)(bh * 64 + d) * SEQ + s0 + sl] = t[sl][d];
  }
}

// ---------------- flash attention: swapped-QK^T 32x32, KVBLK=64, 2-phase dbuf ----
// R3-verbatim structure (passed, 79us, absmax 0.08) + T5 setprio around MFMA
// clusters. grid (BH=32, SEQ/128=16): id%8 = bh%8 -> all q-tiles of one head on
// one XCD (K/V L2-resident; FETCH verified 12.4MB).
__global__ __launch_bounds__(256, 2)
void k_attn(const unsigned short* __restrict__ Q, const unsigned short* __restrict__ Kk,
            const unsigned short* __restrict__ VT, const float* __restrict__ mask,
            unsigned short* __restrict__ ctx) {
  const int tid = threadIdx.x, lane = tid & 63, wave = tid >> 6;
  const int l31 = lane & 31, hi = lane >> 5;
  const int bh = blockIdx.x, b = bh >> 4, h = bh & 15;
  const int qs = blockIdx.y * 128 + wave * 32;    // this wave's 32 q-rows

  __shared__ __align__(16) unsigned short Ks[2][64 * 64];  // [64 key][64 d], swz ^((key&7)<<4)
  __shared__ __align__(16) unsigned short Vs[2][64 * 64];  // [64 d][64 key], swz ^((d&7)<<4)
  __shared__ __align__(16) float sLds[4][32];              // per-wave alpha / l broadcast

  // Q frag (B-operand): lane holds Q[qs+l31][ks*16 + hi*8 + i], i=0..7
  short8 qf[4];
  {
    const unsigned short* qrow = Q + ((size_t)bh * SEQ + qs + l31) * 64 + hi * 8;
    #pragma unroll
    for (int ks = 0; ks < 4; ++ks) qf[ks] = *(const short8*)(qrow + ks * 16);
  }

  f32x16 o0 = {}, o1 = {};          // O[q=crow(r,hi)][d = l31 | 32+l31]
  float mr = -3.0e38f, lr = 0.f;
  const float LOG2E = 1.44269504088896340736f;
  const float scale = 0.125f;       // 1/sqrt(64)
  const int sw = (l31 & 7) << 4;    // read-side XOR swizzle

  auto stage = [&](int bufi, int kt) {
    #pragma unroll
    for (int c = 0; c < 2; ++c) {
      int base = wave * 1024 + c * 4096;
      int off = base + lane * 16;
      int r = off >> 7, cb = off & 127;
      int scb = cb ^ ((r & 7) << 4);               // pre-swizzle the SOURCE
      gload_lds16(Kk + ((size_t)bh * SEQ + kt + r) * 64 + (scb >> 1), &Ks[bufi][base >> 1]);
      gload_lds16(VT + ((size_t)bh * 64 + r) * SEQ + kt + (scb >> 1), &Vs[bufi][base >> 1]);
    }
  };

  stage(0, 0);
  __syncthreads();
  int cur = 0;

  for (int kt = 0; kt < SEQ; kt += 64) {
    if (kt + 64 < SEQ) stage(cur ^ 1, kt + 64);    // issue next-tile loads EARLY

    const char* Kc = (const char*)Ks[cur];
    const char* Vc = (const char*)Vs[cur];

    // ---- S = K Q^T (swapped): s0 = keys kt+0..31, s1 = keys kt+32..63 ----
    f32x16 s0 = {}, s1 = {};
    __builtin_amdgcn_s_setprio(1);
    #pragma unroll
    for (int ks = 0; ks < 4; ++ks) {
      int cb = ((ks * 16 + hi * 8) * 2) ^ sw;
      short8 k0 = *(const short8*)(Kc + l31 * 128 + cb);
      short8 k1 = *(const short8*)(Kc + (32 + l31) * 128 + cb);
      s0 = mfma32x32x16(k0, qf[ks], s0);
      s1 = mfma32x32x16(k1, qf[ks], s1);
    }
    __builtin_amdgcn_s_setprio(0);

    // ---- mask+scale: key(r) = 32*kb + 8*(r>>2) + 4*hi + (r&3) ----
    f32x4 mk0[4], mk1[4];
    #pragma unroll
    for (int rq = 0; rq < 4; ++rq) {
      mk0[rq] = *(const f32x4*)(mask + b * SEQ + kt + rq * 8 + hi * 4);
      mk1[rq] = *(const f32x4*)(mask + b * SEQ + kt + 32 + rq * 8 + hi * 4);
    }
    #pragma unroll
    for (int r = 0; r < 16; ++r) {
      s0[r] = fmaf(s0[r], scale, mk0[r >> 2][r & 3]);
      s1[r] = fmaf(s1[r], scale, mk1[r >> 2][r & 3]);
    }

    // ---- online softmax (per q = l31; partner lane hi^1 has other 32 keys) ----
    float tmax = fmaxf(s0[0], s1[0]);
    #pragma unroll
    for (int r = 1; r < 16; ++r) tmax = fmaxf(tmax, fmaxf(s0[r], s1[r]));
    tmax = xhalf_max(tmax);

    if (!__all(tmax <= mr + 8.0f)) {          // defer-max (T13, THR=8)
      float mnew = fmaxf(mr, tmax);
      float alpha = exp2f((mr - mnew) * LOG2E);
      mr = mnew; lr *= alpha;
      if (hi == 0) sLds[wave][l31] = alpha;   // redistribute alpha: col-index -> row-index
      f32x4 av[4];
      #pragma unroll
      for (int rq = 0; rq < 4; ++rq) av[rq] = *(const f32x4*)&sLds[wave][rq * 8 + hi * 4];
      #pragma unroll
      for (int r = 0; r < 16; ++r) {
        o0[r] *= av[r >> 2][r & 3];
        o1[r] *= av[r >> 2][r & 3];
      }
    }

    float mL = mr * LOG2E;
    float rs = 0.f;
    #pragma unroll
    for (int r = 0; r < 16; ++r) {
      float p0 = exp2f(fmaf(s0[r], LOG2E, -mL));
      float p1 = exp2f(fmaf(s1[r], LOG2E, -mL));
      s0[r] = p0; s1[r] = p1; rs += p0 + p1;
    }
    lr += xhalf_sum(rs);

    // ---- P -> bf16 A-frags via cvt_pk + permlane32_swap (T12) ----
    unsigned pw[4][4];
    #pragma unroll
    for (int ks = 0; ks < 4; ++ks) {
      int ro = 8 * (ks & 1);
      unsigned a0, a1, b0, b1;
      if (ks < 2) {
        a0 = cvtpk(s0[ro + 0], s0[ro + 1]); a1 = cvtpk(s0[ro + 2], s0[ro + 3]);
        b0 = cvtpk(s0[ro + 4], s0[ro + 5]); b1 = cvtpk(s0[ro + 6], s0[ro + 7]);
      } else {
        a0 = cvtpk(s1[ro + 0], s1[ro + 1]); a1 = cvtpk(s1[ro + 2], s1[ro + 3]);
        b0 = cvtpk(s1[ro + 4], s1[ro + 5]); b1 = cvtpk(s1[ro + 6], s1[ro + 7]);
      }
      perm32swap(a0, b0);
      perm32swap(a1, b1);
      pw[ks][0] = a0; pw[ks][1] = a1; pw[ks][2] = b0; pw[ks][3] = b1;
    }

    // ---- O += P V ----
    __builtin_amdgcn_s_setprio(1);
    #pragma unroll
    for (int ks = 0; ks < 4; ++ks) {
      union { unsigned u[4]; short8 s8; } pu;
      pu.u[0] = pw[ks][0]; pu.u[1] = pw[ks][1]; pu.u[2] = pw[ks][2]; pu.u[3] = pw[ks][3];
      int cb = ((ks * 16 + hi * 8) * 2) ^ sw;
      short8 v0 = *(const short8*)(Vc + l31 * 128 + cb);
      short8 v1 = *(const short8*)(Vc + (32 + l31) * 128 + cb);
      o0 = mfma32x32x16(pu.s8, v0, o0);
      o1 = mfma32x32x16(pu.s8, v1, o1);
    }
    __builtin_amdgcn_s_setprio(0);

    __syncthreads();   // drains vmcnt (next-tile loads issued long ago) + protects buf reuse
    cur ^= 1;
  }

  // ---- epilogue: redistribute l (col-index -> row-index), normalize, store ----
  if (hi == 0) sLds[wave][l31] = lr;
  f32x4 lv[4];
  #pragma unroll
  for (int rq = 0; rq < 4; ++rq) {
    f32x4 t = *(const f32x4*)&sLds[wave][rq * 8 + hi * 4];
    lv[rq][0] = 1.f / t[0]; lv[rq][1] = 1.f / t[1];
    lv[rq][2] = 1.f / t[2]; lv[rq][3] = 1.f / t[3];
  }
  #pragma unroll
  for (int r = 0; r < 16; ++r) {
    int q = qs + (r & 3) + 8 * (r >> 2) + 4 * hi;
    float inv = lv[r >> 2][r & 3];
    unsigned short* dst = ctx + (size_t)(b * SEQ + q) * HID + h * 64;
    dst[l31]      = f2bf(o0[r] * inv);
    dst[32 + l31] = f2bf(o1[r] * inv);
  }
}

// ---------------- LayerNorm (input already has residual folded in) ----------------
__global__ __launch_bounds__(256)
void k_ln(const float* __restrict__ resid, const float* __restrict__ gamma,
          const float* __restrict__ beta, float* __restrict__ out) {
  int row = blockIdx.x, tid = threadIdx.x;
  f32x4 v = ((const f32x4*)(resid + (size_t)row * HID))[tid];
  float s = v[0] + v[1] + v[2] + v[3];
  float ss = v[0]*v[0] + v[1]*v[1] + v[2]*v[2] + v[3]*v[3];
  #pragma unroll
  for (int off = 1; off < 64; off <<= 1) { s += __shfl_xor(s, off); ss += __shfl_xor(ss, off); }
  __shared__ float sb[4], ssb[4];
  int wave = tid >> 6, lane = tid & 63;
  if (lane == 0) { sb[wave] = s; ssb[wave] = ss; }
  __syncthreads();
  float ts = sb[0] + sb[1] + sb[2] + sb[3];
  float tss = ssb[0] + ssb[1] + ssb[2] + ssb[3];
  float mu = ts * (1.f / HID);
  float var = tss * (1.f / HID) - mu * mu;
  float rstd = rsqrtf(var + LN_EPS);
  f32x4 g = ((const f32x4*)gamma)[tid];
  f32x4 be = ((const f32x4*)beta)[tid];
  f32x4 o;
  #pragma unroll
  for (int i = 0; i < 4; ++i) o[i] = (v[i] - mu) * rstd * g[i] + be[i];
  ((f32x4*)(out + (size_t)row * HID))[tid] = o;
}

extern "C" void kernel_launch(void* const* d_in, const int* in_sizes, int n_in,
                              void* d_out, int out_size, void* d_ws, size_t ws_size,
                              hipStream_t stream) {
  const float* x     = (const float*)d_in[0];
  const float* mask  = (const float*)d_in[1];
  const float* Wq    = (const float*)d_in[2];
  const float* bq    = (const float*)d_in[3];
  const float* Wk    = (const float*)d_in[4];
  const float* bk    = (const float*)d_in[5];
  const float* Wv    = (const float*)d_in[6];
  const float* bv    = (const float*)d_in[7];
  const float* Wo    = (const float*)d_in[8];
  const float* bo    = (const float*)d_in[9];
  const float* gamma = (const float*)d_in[10];
  const float* beta  = (const float*)d_in[11];
  float* out = (float*)d_out;

  char* w = (char*)d_ws;
  unsigned short* xb    = (unsigned short*)w; w += (size_t)NTOK * HID * 2;   // 8 MB
  unsigned short* WqkvT = (unsigned short*)w; w += (size_t)3 * HID * HID * 2;// 6 MB
  unsigned short* WoT   = (unsigned short*)w; w += (size_t)HID * HID * 2;    // 2 MB
  unsigned short* Qh    = (unsigned short*)w; w += (size_t)NTOK * HID * 2;   // 8 MB
  unsigned short* Kh    = (unsigned short*)w; w += (size_t)NTOK * HID * 2;   // 8 MB
  unsigned short* Vh    = (unsigned short*)w; w += (size_t)NTOK * HID * 2;   // 8 MB
  unsigned short* VTh   = (unsigned short*)w; w += (size_t)NTOK * HID * 2;   // 8 MB
  unsigned short* ctxb  = (unsigned short*)w; w += (size_t)NTOK * HID * 2;   // 8 MB
  float*          attn  = (float*)w;          w += (size_t)NTOK * HID * 4;   // 16 MB
  (void)ws_size; (void)in_sizes; (void)n_in; (void)out_size;

  k_prep<<<dim3(32, 32, 5), dim3(32, 8), 0, stream>>>(Wq, Wk, Wv, Wo, x, WqkvT, WoT, xb);

  k_gemm<0><<<768, 256, 0, stream>>>(
      xb, WqkvT, NTOK, 3 * HID, HID, bq, bk, bv, nullptr, Qh, Kh, Vh, nullptr);

  k_vtrans<<<dim3(SEQ / 64, BATCH * NUMH), 256, 0, stream>>>(Vh, VTh);

  k_attn<<<dim3(BATCH * NUMH, SEQ / 128), 256, 0, stream>>>(Qh, Kh, VTh, mask, ctxb);

  k_gemm<1><<<256, 256, 0, stream>>>(
      ctxb, WoT, NTOK, HID, HID, bo, nullptr, nullptr, x, nullptr, nullptr, nullptr, attn);

  k_ln<<<NTOK, 256, 0, stream>>>(attn, gamma, beta, out);
}

// Round 8
// 233.775 us; speedup vs baseline: 1.0224x; 1.0224x over previous
//
#include <hip/hip_runtime.h>
#include <hip/hip_bf16.h>
#include <stdint.h>

#define NUMH 16
#define HD   64
#define HID  1024
#define SEQ  2048
#define BATCH 2
#define NTOK (BATCH*SEQ)   // 4096
#define LN_EPS 1e-5f

typedef __attribute__((ext_vector_type(8)))  short  short8;   // 8 bf16 (4 VGPRs)
typedef __attribute__((ext_vector_type(4)))  float  f32x4;
typedef __attribute__((ext_vector_type(16))) float  f32x16;

#define AS1 __attribute__((address_space(1)))
#define AS3 __attribute__((address_space(3)))

__device__ __forceinline__ void gload_lds16(const void* g, void* l) {
  // LDS dest = wave-uniform base + lane*16 (HW); global addr is per-lane.
  __builtin_amdgcn_global_load_lds((const AS1 void*)g, (AS3 void*)l, 16, 0, 0);
}

__device__ __forceinline__ unsigned short f2bf(float f) {
  union { float f; unsigned u; } v; v.f = f;
  unsigned u = v.u;
  u += 0x7fffu + ((u >> 16) & 1u);   // RNE
  return (unsigned short)(u >> 16);
}

__device__ __forceinline__ f32x4 mfma16x16x32(short8 a, short8 b, f32x4 c) {
  return __builtin_amdgcn_mfma_f32_16x16x32_bf16(a, b, c, 0, 0, 0);
}
__device__ __forceinline__ f32x16 mfma32x32x16(short8 a, short8 b, f32x16 c) {
  return __builtin_amdgcn_mfma_f32_32x32x16_bf16(a, b, c, 0, 0, 0);
}

// pack two f32 -> dword of 2 bf16 (lo = first arg), HW RNE
__device__ __forceinline__ unsigned cvtpk(float lo, float hi) {
  unsigned r;
  asm("v_cvt_pk_bf16_f32 %0, %1, %2" : "=v"(r) : "v"(lo), "v"(hi));
  return r;
}
// swap upper 32 lanes of a with lower 32 lanes of b (both modified)
__device__ __forceinline__ void perm32swap(unsigned &a, unsigned &b) {
  asm volatile("v_permlane32_swap_b32 %0, %1" : "+v"(a), "+v"(b));
}
// cross-half (lane i <-> lane i^32) reduce helpers via permlane32_swap
__device__ __forceinline__ float xhalf_max(float x) {
  union { float f; unsigned u; } a, b; a.f = x; b.f = x;
  perm32swap(a.u, b.u);
  return fmaxf(a.f, b.f);
}
__device__ __forceinline__ float xhalf_sum(float x) {
  union { float f; unsigned u; } a, b; a.f = x; b.f = x;
  perm32swap(a.u, b.u);
  return a.f + b.f;
}

// -------- fused: weight transposes (z=0..3) + x fp32->bf16 conversion (z=4) --------
__global__ void k_prep(const float* __restrict__ Wq, const float* __restrict__ Wk,
                       const float* __restrict__ Wv, const float* __restrict__ Wo,
                       const float* __restrict__ x,
                       unsigned short* __restrict__ WqkvT, unsigned short* __restrict__ WoT,
                       unsigned short* __restrict__ xb) {
  int z = blockIdx.z;
  int tx = threadIdx.x, ty = threadIdx.y;           // 32 x 8
  if (z == 4) {
    // x conversion: 1024 blocks x 256 thr x 4 f32x4
    int tid = ty * 32 + tx;
    size_t i0 = ((size_t)(blockIdx.y * 32 + blockIdx.x) * 256 + tid) * 4;
    #pragma unroll
    for (int u = 0; u < 4; ++u) {
      f32x4 v = ((const f32x4*)x)[i0 + u];
      unsigned short* o = xb + (i0 + u) * 4;
      o[0] = f2bf(v[0]); o[1] = f2bf(v[1]); o[2] = f2bf(v[2]); o[3] = f2bf(v[3]);
    }
    return;
  }
  __shared__ float t[32][33];
  const float* in = (z == 0) ? Wq : (z == 1) ? Wk : (z == 2) ? Wv : Wo;
  unsigned short* out = (z < 3) ? WqkvT + (size_t)z * HID * HID : WoT;
  int x0 = blockIdx.x * 32, y0 = blockIdx.y * 32;
  for (int j = 0; j < 32; j += 8)
    t[ty + j][tx] = in[(y0 + ty + j) * HID + x0 + tx];
  __syncthreads();
  for (int j = 0; j < 32; j += 8)
    out[(x0 + ty + j) * HID + y0 + tx] = f2bf(t[tx][ty + j]);
}

// ---------------- GEMM: C[M][N] = A[M][K](bf16) * BT[N][K](bf16)^T ----------------
// m97 geometry: 128x128 tile, BK=64, 4 waves (2x2). 1D grid with XCD 2D-chunked
// mapping (T1). MODE 0: QKV epilogue scatter; MODE 1: fp32 + fused residual.
template<int MODE>
__global__ __launch_bounds__(256, 2)
void k_gemm(const unsigned short* __restrict__ A, const unsigned short* __restrict__ BT,
            int M, int N, int K,
            const float* __restrict__ bias0, const float* __restrict__ bias1,
            const float* __restrict__ bias2, const float* __restrict__ resid,
            unsigned short* __restrict__ outQ, unsigned short* __restrict__ outK,
            unsigned short* __restrict__ outV, float* __restrict__ outF) {
  const int tid  = threadIdx.x;
  const int lane = tid & 63, wave = tid >> 6;
  const int l15 = lane & 15, lhi = lane >> 4;
  const int orig = blockIdx.x;
  const int xcd = orig & 7, i2 = orig >> 3;
  const int rb  = (xcd & 3) * 8 + (i2 & 7);
  const int cb2 = (MODE == 0) ? (xcd >> 2) * 12 + (i2 >> 3)
                              : (xcd >> 2) * 4  + (i2 >> 3);
  const int row0 = rb * 128, col0 = cb2 * 128;
  const int wrow = (wave >> 1) * 64, wcol = (wave & 1) * 64;

  __shared__ unsigned short As[128 * 64];   // [128 row][64 bf16] = 128B rows
  __shared__ unsigned short Bs[128 * 64];

  f32x4 acc[4][4] = {};

  for (int kt = 0; kt < K; kt += 64) {
    #pragma unroll
    for (int c = 0; c < 4; ++c) {
      int base = wave * 1024 + c * 4096;            // byte base (wave-uniform)
      int o = base + lane * 16;                     // this lane's byte offset
      int r = o >> 7, cb = o & 127;                 // row, col-byte (128B rows)
      gload_lds16(A  + (size_t)(row0 + r) * K + kt + (cb >> 1), As + (base >> 1));
      gload_lds16(BT + (size_t)(col0 + r) * K + kt + (cb >> 1), Bs + (base >> 1));
    }
    __syncthreads();

    #pragma unroll
    for (int kk = 0; kk < 2; ++kk) {
      short8 af[4], bf[4];
      #pragma unroll
      for (int m = 0; m < 4; ++m)
        af[m] = *(const short8*)(As + (wrow + m * 16 + l15) * 64 + kk * 32 + lhi * 8);
      #pragma unroll
      for (int n = 0; n < 4; ++n)
        bf[n] = *(const short8*)(Bs + (wcol + n * 16 + l15) * 64 + kk * 32 + lhi * 8);
      #pragma unroll
      for (int m = 0; m < 4; ++m)
        #pragma unroll
        for (int n = 0; n < 4; ++n)
          acc[m][n] = mfma16x16x32(af[m], bf[n], acc[m][n]);
    }
    __syncthreads();
  }

  #pragma unroll
  for (int m = 0; m < 4; ++m)
    #pragma unroll
    for (int n = 0; n < 4; ++n) {
      int col = col0 + wcol + n * 16 + l15;
      #pragma unroll
      for (int j = 0; j < 4; ++j) {
        int row = row0 + wrow + m * 16 + lhi * 4 + j;
        float v = acc[m][n][j];
        if (MODE == 0) {
          int proj = col >> 10, d = col & 1023;
          int h = d >> 6, hd = d & 63;
          int b = row >> 11, s = row & 2047;
          const float* bias = (proj == 0) ? bias0 : (proj == 1) ? bias1 : bias2;
          unsigned short* dst = (proj == 0) ? outQ : (proj == 1) ? outK : outV;
          dst[((size_t)((b * NUMH + h) * SEQ + s) << 6) + hd] = f2bf(v + bias[d]);
        } else {
          size_t idx = (size_t)row * N + col;
          outF[idx] = v + bias0[col] + resid[idx];
        }
      }
    }
}

// ---------------- V [BH][S][64] -> VT [BH][64][S] (bf16) ----------------
__global__ void k_vtrans(const unsigned short* __restrict__ V, unsigned short* __restrict__ VT) {
  __shared__ unsigned short t[64][65];
  int bh = blockIdx.y, s0 = blockIdx.x * 64;
  int tid = threadIdx.x;
  for (int it = 0; it < 16; ++it) {
    int idx = it * 256 + tid;
    int r = idx >> 6, c = idx & 63;
    t[r][c] = V[(size_t)(bh * SEQ + s0 + r) * 64 + c];
  }
  __syncthreads();
  for (int it = 0; it < 16; ++it) {
    int idx = it * 256 + tid;
    int d = idx >> 6, sl = idx & 63;
    VT[(size_t)(bh * 64 + d) * SEQ + s0 + sl] = t[sl][d];
  }
}

// ---------------- flash attention: swapped-QK^T 32x32, KVBLK=64, 2-phase dbuf ----
// R3-verbatim loop body (passed at 79us / absmax 0.078). NO setprio: R6 A/B
// measured it at -11.5us on this barrier-locked 4-wave structure (m190 lockstep
// null reproduced). NO split-KV: R7 failed validation (0.117 > 0.1).
// grid (BH=32, SEQ/128=16): id%8 = bh%8 -> all q-tiles of one head on one XCD
// (K/V L2-resident; FETCH verified 12.4MB).
__global__ __launch_bounds__(256, 2)
void k_attn(const unsigned short* __restrict__ Q, const unsigned short* __restrict__ Kk,
            const unsigned short* __restrict__ VT, const float* __restrict__ mask,
            unsigned short* __restrict__ ctx) {
  const int tid = threadIdx.x, lane = tid & 63, wave = tid >> 6;
  const int l31 = lane & 31, hi = lane >> 5;
  const int bh = blockIdx.x, b = bh >> 4, h = bh & 15;
  const int qs = blockIdx.y * 128 + wave * 32;    // this wave's 32 q-rows

  __shared__ __align__(16) unsigned short Ks[2][64 * 64];  // [64 key][64 d], swz ^((key&7)<<4)
  __shared__ __align__(16) unsigned short Vs[2][64 * 64];  // [64 d][64 key], swz ^((d&7)<<4)
  __shared__ __align__(16) float sLds[4][32];              // per-wave alpha / l broadcast

  // Q frag (B-operand): lane holds Q[qs+l31][ks*16 + hi*8 + i], i=0..7
  short8 qf[4];
  {
    const unsigned short* qrow = Q + ((size_t)bh * SEQ + qs + l31) * 64 + hi * 8;
    #pragma unroll
    for (int ks = 0; ks < 4; ++ks) qf[ks] = *(const short8*)(qrow + ks * 16);
  }

  f32x16 o0 = {}, o1 = {};          // O[q=crow(r,hi)][d = l31 | 32+l31]
  float mr = -3.0e38f, lr = 0.f;
  const float LOG2E = 1.44269504088896340736f;
  const float scale = 0.125f;       // 1/sqrt(64)
  const int sw = (l31 & 7) << 4;    // read-side XOR swizzle

  auto stage = [&](int bufi, int kt) {
    #pragma unroll
    for (int c = 0; c < 2; ++c) {
      int base = wave * 1024 + c * 4096;
      int off = base + lane * 16;
      int r = off >> 7, cb = off & 127;
      int scb = cb ^ ((r & 7) << 4);               // pre-swizzle the SOURCE
      gload_lds16(Kk + ((size_t)bh * SEQ + kt + r) * 64 + (scb >> 1), &Ks[bufi][base >> 1]);
      gload_lds16(VT + ((size_t)bh * 64 + r) * SEQ + kt + (scb >> 1), &Vs[bufi][base >> 1]);
    }
  };

  stage(0, 0);
  __syncthreads();
  int cur = 0;

  for (int kt = 0; kt < SEQ; kt += 64) {
    if (kt + 64 < SEQ) stage(cur ^ 1, kt + 64);    // issue next-tile loads EARLY

    const char* Kc = (const char*)Ks[cur];
    const char* Vc = (const char*)Vs[cur];

    // ---- S = K Q^T (swapped): s0 = keys kt+0..31, s1 = keys kt+32..63 ----
    f32x16 s0 = {}, s1 = {};
    #pragma unroll
    for (int ks = 0; ks < 4; ++ks) {
      int cb = ((ks * 16 + hi * 8) * 2) ^ sw;
      short8 k0 = *(const short8*)(Kc + l31 * 128 + cb);
      short8 k1 = *(const short8*)(Kc + (32 + l31) * 128 + cb);
      s0 = mfma32x32x16(k0, qf[ks], s0);
      s1 = mfma32x32x16(k1, qf[ks], s1);
    }

    // ---- mask+scale: key(r) = 32*kb + 8*(r>>2) + 4*hi + (r&3) ----
    f32x4 mk0[4], mk1[4];
    #pragma unroll
    for (int rq = 0; rq < 4; ++rq) {
      mk0[rq] = *(const f32x4*)(mask + b * SEQ + kt + rq * 8 + hi * 4);
      mk1[rq] = *(const f32x4*)(mask + b * SEQ + kt + 32 + rq * 8 + hi * 4);
    }
    #pragma unroll
    for (int r = 0; r < 16; ++r) {
      s0[r] = fmaf(s0[r], scale, mk0[r >> 2][r & 3]);
      s1[r] = fmaf(s1[r], scale, mk1[r >> 2][r & 3]);
    }

    // ---- online softmax (per q = l31; partner lane hi^1 has other 32 keys) ----
    float tmax = fmaxf(s0[0], s1[0]);
    #pragma unroll
    for (int r = 1; r < 16; ++r) tmax = fmaxf(tmax, fmaxf(s0[r], s1[r]));
    tmax = xhalf_max(tmax);

    if (!__all(tmax <= mr + 8.0f)) {          // defer-max (T13, THR=8)
      float mnew = fmaxf(mr, tmax);
      float alpha = exp2f((mr - mnew) * LOG2E);
      mr = mnew; lr *= alpha;
      if (hi == 0) sLds[wave][l31] = alpha;   // redistribute alpha: col-index -> row-index
      f32x4 av[4];
      #pragma unroll
      for (int rq = 0; rq < 4; ++rq) av[rq] = *(const f32x4*)&sLds[wave][rq * 8 + hi * 4];
      #pragma unroll
      for (int r = 0; r < 16; ++r) {
        o0[r] *= av[r >> 2][r & 3];
        o1[r] *= av[r >> 2][r & 3];
      }
    }

    float mL = mr * LOG2E;
    float rs = 0.f;
    #pragma unroll
    for (int r = 0; r < 16; ++r) {
      float p0 = exp2f(fmaf(s0[r], LOG2E, -mL));
      float p1 = exp2f(fmaf(s1[r], LOG2E, -mL));
      s0[r] = p0; s1[r] = p1; rs += p0 + p1;
    }
    lr += xhalf_sum(rs);

    // ---- P -> bf16 A-frags via cvt_pk + permlane32_swap (T12) ----
    unsigned pw[4][4];
    #pragma unroll
    for (int ks = 0; ks < 4; ++ks) {
      int ro = 8 * (ks & 1);
      unsigned a0, a1, b0, b1;
      if (ks < 2) {
        a0 = cvtpk(s0[ro + 0], s0[ro + 1]); a1 = cvtpk(s0[ro + 2], s0[ro + 3]);
        b0 = cvtpk(s0[ro + 4], s0[ro + 5]); b1 = cvtpk(s0[ro + 6], s0[ro + 7]);
      } else {
        a0 = cvtpk(s1[ro + 0], s1[ro + 1]); a1 = cvtpk(s1[ro + 2], s1[ro + 3]);
        b0 = cvtpk(s1[ro + 4], s1[ro + 5]); b1 = cvtpk(s1[ro + 6], s1[ro + 7]);
      }
      perm32swap(a0, b0);
      perm32swap(a1, b1);
      pw[ks][0] = a0; pw[ks][1] = a1; pw[ks][2] = b0; pw[ks][3] = b1;
    }

    // ---- O += P V ----
    #pragma unroll
    for (int ks = 0; ks < 4; ++ks) {
      union { unsigned u[4]; short8 s8; } pu;
      pu.u[0] = pw[ks][0]; pu.u[1] = pw[ks][1]; pu.u[2] = pw[ks][2]; pu.u[3] = pw[ks][3];
      int cb = ((ks * 16 + hi * 8) * 2) ^ sw;
      short8 v0 = *(const short8*)(Vc + l31 * 128 + cb);
      short8 v1 = *(const short8*)(Vc + (32 + l31) * 128 + cb);
      o0 = mfma32x32x16(pu.s8, v0, o0);
      o1 = mfma32x32x16(pu.s8, v1, o1);
    }

    __syncthreads();   // drains vmcnt (next-tile loads issued long ago) + protects buf reuse
    cur ^= 1;
  }

  // ---- epilogue: redistribute l (col-index -> row-index), normalize, store ----
  if (hi == 0) sLds[wave][l31] = lr;
  f32x4 lv[4];
  #pragma unroll
  for (int rq = 0; rq < 4; ++rq) {
    f32x4 t = *(const f32x4*)&sLds[wave][rq * 8 + hi * 4];
    lv[rq][0] = 1.f / t[0]; lv[rq][1] = 1.f / t[1];
    lv[rq][2] = 1.f / t[2]; lv[rq][3] = 1.f / t[3];
  }
  #pragma unroll
  for (int r = 0; r < 16; ++r) {
    int q = qs + (r & 3) + 8 * (r >> 2) + 4 * hi;
    float inv = lv[r >> 2][r & 3];
    unsigned short* dst = ctx + (size_t)(b * SEQ + q) * HID + h * 64;
    dst[l31]      = f2bf(o0[r] * inv);
    dst[32 + l31] = f2bf(o1[r] * inv);
  }
}

// ---------------- LayerNorm (input already has residual folded in) ----------------
__global__ __launch_bounds__(256)
void k_ln(const float* __restrict__ resid, const float* __restrict__ gamma,
          const float* __restrict__ beta, float* __restrict__ out) {
  int row = blockIdx.x, tid = threadIdx.x;
  f32x4 v = ((const f32x4*)(resid + (size_t)row * HID))[tid];
  float s = v[0] + v[1] + v[2] + v[3];
  float ss = v[0]*v[0] + v[1]*v[1] + v[2]*v[2] + v[3]*v[3];
  #pragma unroll
  for (int off = 1; off < 64; off <<= 1) { s += __shfl_xor(s, off); ss += __shfl_xor(ss, off); }
  __shared__ float sb[4], ssb[4];
  int wave = tid >> 6, lane = tid & 63;
  if (lane == 0) { sb[wave] = s; ssb[wave] = ss; }
  __syncthreads();
  float ts = sb[0] + sb[1] + sb[2] + sb[3];
  float tss = ssb[0] + ssb[1] + ssb[2] + ssb[3];
  float mu = ts * (1.f / HID);
  float var = tss * (1.f / HID) - mu * mu;
  float rstd = rsqrtf(var + LN_EPS);
  f32x4 g = ((const f32x4*)gamma)[tid];
  f32x4 be = ((const f32x4*)beta)[tid];
  f32x4 o;
  #pragma unroll
  for (int i = 0; i < 4; ++i) o[i] = (v[i] - mu) * rstd * g[i] + be[i];
  ((f32x4*)(out + (size_t)row * HID))[tid] = o;
}

extern "C" void kernel_launch(void* const* d_in, const int* in_sizes, int n_in,
                              void* d_out, int out_size, void* d_ws, size_t ws_size,
                              hipStream_t stream) {
  const float* x     = (const float*)d_in[0];
  const float* mask  = (const float*)d_in[1];
  const float* Wq    = (const float*)d_in[2];
  const float* bq    = (const float*)d_in[3];
  const float* Wk    = (const float*)d_in[4];
  const float* bk    = (const float*)d_in[5];
  const float* Wv    = (const float*)d_in[6];
  const float* bv    = (const float*)d_in[7];
  const float* Wo    = (const float*)d_in[8];
  const float* bo    = (const float*)d_in[9];
  const float* gamma = (const float*)d_in[10];
  const float* beta  = (const float*)d_in[11];
  float* out = (float*)d_out;

  char* w = (char*)d_ws;
  unsigned short* xb    = (unsigned short*)w; w += (size_t)NTOK * HID * 2;   // 8 MB
  unsigned short* WqkvT = (unsigned short*)w; w += (size_t)3 * HID * HID * 2;// 6 MB
  unsigned short* WoT   = (unsigned short*)w; w += (size_t)HID * HID * 2;    // 2 MB
  unsigned short* Qh    = (unsigned short*)w; w += (size_t)NTOK * HID * 2;   // 8 MB
  unsigned short* Kh    = (unsigned short*)w; w += (size_t)NTOK * HID * 2;   // 8 MB
  unsigned short* Vh    = (unsigned short*)w; w += (size_t)NTOK * HID * 2;   // 8 MB
  unsigned short* VTh   = (unsigned short*)w; w += (size_t)NTOK * HID * 2;   // 8 MB
  unsigned short* ctxb  = (unsigned short*)w; w += (size_t)NTOK * HID * 2;   // 8 MB
  float*          attn  = (float*)w;          w += (size_t)NTOK * HID * 4;   // 16 MB
  (void)ws_size; (void)in_sizes; (void)n_in; (void)out_size;

  k_prep<<<dim3(32, 32, 5), dim3(32, 8), 0, stream>>>(Wq, Wk, Wv, Wo, x, WqkvT, WoT, xb);

  k_gemm<0><<<768, 256, 0, stream>>>(
      xb, WqkvT, NTOK, 3 * HID, HID, bq, bk, bv, nullptr, Qh, Kh, Vh, nullptr);

  k_vtrans<<<dim3(SEQ / 64, BATCH * NUMH), 256, 0, stream>>>(Vh, VTh);

  k_attn<<<dim3(BATCH * NUMH, SEQ / 128), 256, 0, stream>>>(Qh, Kh, VTh, mask, ctxb);

  k_gemm<1><<<256, 256, 0, stream>>>(
      ctxb, WoT, NTOK, HID, HID, bo, nullptr, nullptr, x, nullptr, nullptr, nullptr, attn);

  k_ln<<<NTOK, 256, 0, stream>>>(attn, gamma, beta, out);
}